// Round 1
// baseline (16585.405 us; speedup 1.0000x reference)
//
#include <hip/hip_runtime.h>

// Problem constants
#define TSEQ 512
#define NB   32     // batch
#define DB   768    // d_bert
#define H2E  128    // encoder hidden per dir
#define DL   256    // d_lstm
#define NC   16     // n_class

__device__ __forceinline__ float sigf(float x) { return 1.0f / (1.0f + __expf(-x)); }
__device__ __forceinline__ float tanhfast(float x) { return 1.0f - 2.0f / (1.0f + __expf(2.0f * x)); }

// ---------------------------------------------------------------------------
// Generic f32 GEMM: C[remap(m), n] = sum_k A[m,k]*W[n,k] + b1[n] + b2[n]
// 64x64 tile, BK=16, 256 threads, 4x4 microtile.
// MODE 0: direct rows. MODE 1: m=b*T+t -> out row t*NB+b. MODE 2: -> (T-1-t)*NB+b.
// M must be a multiple of 64, K a multiple of 16. N arbitrary (guarded).
// ---------------------------------------------------------------------------
template <int MODE>
__global__ __launch_bounds__(256) void gemm_nt(
    const float* __restrict__ A, int lda,
    const float* __restrict__ W, int ldw,
    const float* __restrict__ b1, const float* __restrict__ b2,
    float* __restrict__ C, int ldc, int N, int K)
{
    __shared__ float As[16][68];
    __shared__ float Ws[16][68];
    const int tid = threadIdx.x;
    const int m0 = blockIdx.x * 64;
    const int n0 = blockIdx.y * 64;
    const int tx = tid & 15, ty = tid >> 4;
    const int lrow = tid >> 2;
    const int lk = (tid & 3) * 4;
    float acc[4][4] = {};

    for (int k0 = 0; k0 < K; k0 += 16) {
        float4 av = *(const float4*)(A + (size_t)(m0 + lrow) * lda + k0 + lk);
        float4 wv = make_float4(0.f, 0.f, 0.f, 0.f);
        if (n0 + lrow < N)
            wv = *(const float4*)(W + (size_t)(n0 + lrow) * ldw + k0 + lk);
        As[lk + 0][lrow] = av.x; As[lk + 1][lrow] = av.y;
        As[lk + 2][lrow] = av.z; As[lk + 3][lrow] = av.w;
        Ws[lk + 0][lrow] = wv.x; Ws[lk + 1][lrow] = wv.y;
        Ws[lk + 2][lrow] = wv.z; Ws[lk + 3][lrow] = wv.w;
        __syncthreads();
#pragma unroll
        for (int kk = 0; kk < 16; ++kk) {
            float a0 = As[kk][ty * 4 + 0], a1 = As[kk][ty * 4 + 1];
            float a2 = As[kk][ty * 4 + 2], a3 = As[kk][ty * 4 + 3];
            float w0 = Ws[kk][tx * 4 + 0], w1 = Ws[kk][tx * 4 + 1];
            float w2 = Ws[kk][tx * 4 + 2], w3 = Ws[kk][tx * 4 + 3];
            acc[0][0] += a0 * w0; acc[0][1] += a0 * w1; acc[0][2] += a0 * w2; acc[0][3] += a0 * w3;
            acc[1][0] += a1 * w0; acc[1][1] += a1 * w1; acc[1][2] += a1 * w2; acc[1][3] += a1 * w3;
            acc[2][0] += a2 * w0; acc[2][1] += a2 * w1; acc[2][2] += a2 * w2; acc[2][3] += a2 * w3;
            acc[3][0] += a3 * w0; acc[3][1] += a3 * w1; acc[3][2] += a3 * w2; acc[3][3] += a3 * w3;
        }
        __syncthreads();
    }

#pragma unroll
    for (int i = 0; i < 4; ++i) {
        int gm = m0 + ty * 4 + i;
        int orow;
        if (MODE == 0) orow = gm;
        else {
            int bb = gm >> 9;          // /TSEQ
            int tt = gm & (TSEQ - 1);
            orow = (MODE == 1 ? tt : (TSEQ - 1 - tt)) * NB + bb;
        }
#pragma unroll
        for (int j = 0; j < 4; ++j) {
            int gn = n0 + tx * 4 + j;
            if (gn < N) {
                float bias = (b1 ? b1[gn] : 0.f) + (b2 ? b2[gn] : 0.f);
                C[(size_t)orow * ldc + gn] = acc[i][j] + bias;
            }
        }
    }
}

// ---------------------------------------------------------------------------
// Encoder LSTM scan. 64 blocks: blockIdx.x = b*2 + dir. 512 threads, 1 gate each.
// Whh row (128 f32) lives in registers. h broadcast via LDS.
// G is time-major (T, NB, 512) with biases pre-added; dir=1 uses time-reversed G.
// Writes h into hs_ctx[(b*T + t)*512 + dir*128 + j].
// ---------------------------------------------------------------------------
__global__ __launch_bounds__(512) void enc_scan(
    const float* __restrict__ Gf, const float* __restrict__ Gr,
    const float* __restrict__ Whh_f, const float* __restrict__ Whh_r,
    float* __restrict__ hs_ctx)
{
    const int dir = blockIdx.x & 1;
    const int b = blockIdx.x >> 1;
    const float* __restrict__ G = dir ? Gr : Gf;
    const float* __restrict__ Whh = dir ? Whh_r : Whh_f;
    const int j = threadIdx.x;   // gate 0..511

    __shared__ float4 h4[H2E / 4];
    __shared__ float gates[4 * H2E];
    float* h_s = (float*)h4;

    float4 w[32];
#pragma unroll
    for (int k = 0; k < 32; ++k)
        w[k] = *(const float4*)(Whh + (size_t)j * H2E + k * 4);

    float c = 0.f;
    if (j < H2E) h_s[j] = 0.f;
    __syncthreads();

    for (int t = 0; t < TSEQ; ++t) {
        const float* grow = G + ((size_t)t * NB + b) * 512;
        float acc = grow[j];
#pragma unroll
        for (int k = 0; k < 32; ++k) {
            float4 hv = h4[k];
            acc += w[k].x * hv.x + w[k].y * hv.y + w[k].z * hv.z + w[k].w * hv.w;
        }
        gates[j] = acc;
        __syncthreads();
        if (j < H2E) {
            float ig = sigf(gates[j]);
            float fg = sigf(gates[j + H2E]);
            float gg = tanhfast(gates[j + 2 * H2E]);
            float og = sigf(gates[j + 3 * H2E]);
            c = fg * c + ig * gg;
            float h = og * tanhfast(c);
            h_s[j] = h;
            int tout = dir ? (TSEQ - 1 - t) : t;
            hs_ctx[((size_t)b * TSEQ + tout) * 512 + dir * H2E + j] = h;
        }
        __syncthreads();
    }
}

// ---------------------------------------------------------------------------
// Fused additive-attention scores + softmax. One block per (b,i) row.
// a_j = sum_x v[x]*tanh(qp[b,i,x]+kp[b,j,x]); w = softmax_j(a + mask)
// ---------------------------------------------------------------------------
__global__ __launch_bounds__(256) void attn_w(
    const float* __restrict__ qp, const float* __restrict__ kp,
    const int* __restrict__ mask, const float* __restrict__ fc2,
    float* __restrict__ wout)
{
    const int bi = blockIdx.x;       // b*T + i
    const int b = bi >> 9;
    const int tid = threadIdx.x;
    __shared__ float kps[TSEQ * 11];
    __shared__ float red[8];

    const float* kpb = kp + (size_t)b * TSEQ * 10;
    for (int idx = tid; idx < TSEQ * 10; idx += 256) {
        int j = idx / 10, xx = idx - j * 10;
        kps[j * 11 + xx] = kpb[idx];
    }
    float q[10], vv[10];
#pragma unroll
    for (int xx = 0; xx < 10; ++xx) {
        q[xx] = qp[(size_t)bi * 10 + xx];
        vv[xx] = fc2[xx];
    }
    __syncthreads();

    float a[2];
#pragma unroll
    for (int jj = 0; jj < 2; ++jj) {
        int j = tid + jj * 256;
        float s = 0.f;
#pragma unroll
        for (int xx = 0; xx < 10; ++xx)
            s += vv[xx] * tanhfast(q[xx] + kps[j * 11 + xx]);
        if (mask[(size_t)b * TSEQ + j] == 0) s = -1e30f;
        a[jj] = s;
    }

    float m = fmaxf(a[0], a[1]);
#pragma unroll
    for (int o = 32; o >= 1; o >>= 1) m = fmaxf(m, __shfl_xor(m, o));
    if ((tid & 63) == 0) red[tid >> 6] = m;
    __syncthreads();
    m = fmaxf(fmaxf(red[0], red[1]), fmaxf(red[2], red[3]));

    float e0 = __expf(a[0] - m), e1 = __expf(a[1] - m);
    float s = e0 + e1;
#pragma unroll
    for (int o = 32; o >= 1; o >>= 1) s += __shfl_xor(s, o);
    if ((tid & 63) == 0) red[4 + (tid >> 6)] = s;
    __syncthreads();
    s = (red[4] + red[5]) + (red[6] + red[7]);
    float inv = 1.0f / s;
    wout[(size_t)bi * TSEQ + tid] = e0 * inv;
    wout[(size_t)bi * TSEQ + tid + 256] = e1 * inv;
}

// ---------------------------------------------------------------------------
// Batched NN GEMM: ctx[b,i,d] = sum_j w[b,i,j]*hs[b,j,d]; writes hs_ctx cols 256:512
// ---------------------------------------------------------------------------
__global__ __launch_bounds__(256) void bgemm_nn(
    const float* __restrict__ Wmat,  // (NB, T, T)
    float* __restrict__ hs_ctx)      // (NB*T, 512): read cols [0,256), write [256,512)
{
    __shared__ float As[16][68];
    __shared__ float Bs[16][68];
    const int tid = threadIdx.x;
    const int b = blockIdx.z;
    const int i0 = blockIdx.x * 64;
    const int d0 = blockIdx.y * 64;
    const int tx = tid & 15, ty = tid >> 4;
    float acc[4][4] = {};
    const float* Ab = Wmat + (size_t)b * TSEQ * TSEQ;
    const float* Bb = hs_ctx + (size_t)b * TSEQ * 512;

    for (int k0 = 0; k0 < TSEQ; k0 += 16) {
        {
            int r = tid >> 2, kq = (tid & 3) * 4;
            float4 v = *(const float4*)(Ab + (size_t)(i0 + r) * TSEQ + k0 + kq);
            As[kq + 0][r] = v.x; As[kq + 1][r] = v.y; As[kq + 2][r] = v.z; As[kq + 3][r] = v.w;
        }
        {
            int kk = tid >> 4, dq = (tid & 15) * 4;
            float4 v = *(const float4*)(Bb + (size_t)(k0 + kk) * 512 + d0 + dq);
            *(float4*)&Bs[kk][dq] = v;
        }
        __syncthreads();
#pragma unroll
        for (int kk = 0; kk < 16; ++kk) {
            float a0 = As[kk][ty * 4 + 0], a1 = As[kk][ty * 4 + 1];
            float a2 = As[kk][ty * 4 + 2], a3 = As[kk][ty * 4 + 3];
            float b0 = Bs[kk][tx * 4 + 0], b1 = Bs[kk][tx * 4 + 1];
            float b2 = Bs[kk][tx * 4 + 2], b3 = Bs[kk][tx * 4 + 3];
            acc[0][0] += a0 * b0; acc[0][1] += a0 * b1; acc[0][2] += a0 * b2; acc[0][3] += a0 * b3;
            acc[1][0] += a1 * b0; acc[1][1] += a1 * b1; acc[1][2] += a1 * b2; acc[1][3] += a1 * b3;
            acc[2][0] += a2 * b0; acc[2][1] += a2 * b1; acc[2][2] += a2 * b2; acc[2][3] += a2 * b3;
            acc[3][0] += a3 * b0; acc[3][1] += a3 * b1; acc[3][2] += a3 * b2; acc[3][3] += a3 * b3;
        }
        __syncthreads();
    }
#pragma unroll
    for (int i = 0; i < 4; ++i)
#pragma unroll
        for (int j = 0; j < 4; ++j)
            hs_ctx[((size_t)b * TSEQ + i0 + ty * 4 + i) * 512 + 256 + d0 + tx * 4 + j] = acc[i][j];
}

// ---------------------------------------------------------------------------
// Decoder LSTM scan. 32 blocks (one per batch elem), 512 threads, 2 gates each.
// Gd (T,NB,1024) has y_enc projection + biases pre-added. Whh_d streamed from L2.
// ---------------------------------------------------------------------------
__global__ __launch_bounds__(512) void dec_scan(
    const float* __restrict__ Gd,
    const float* __restrict__ Whh,    // (1024,256)
    const float* __restrict__ Wih,    // (1024,272); cols 256:272 multiply y
    const float* __restrict__ lin_w,  // (16,256)
    const float* __restrict__ lin_b,  // (16,)
    const float* __restrict__ hs_ctx,
    float* __restrict__ out)          // (NB, T, 16)
{
    const int b = blockIdx.x;
    const int tid = threadIdx.x;
    __shared__ float4 h4[DL / 4];
    __shared__ float gates[4 * DL];
    __shared__ float y_s[NC];
    float* h_s = (float*)h4;

    if (tid < DL) h_s[tid] = hs_ctx[((size_t)b * TSEQ + (TSEQ - 1)) * 512 + tid];
    if (tid < NC) y_s[tid] = 0.f;
    float c = 0.f;
    __syncthreads();

    for (int t = 0; t < TSEQ; ++t) {
        const float* grow = Gd + ((size_t)t * NB + b) * 1024;
#pragma unroll
        for (int g = 0; g < 2; ++g) {
            int jj = tid + g * 512;
            const float* wr = Whh + (size_t)jj * DL;
            float acc = grow[jj];
            float4 s4 = make_float4(0.f, 0.f, 0.f, 0.f);
#pragma unroll 8
            for (int k = 0; k < DL / 4; ++k) {
                float4 wv = *(const float4*)(wr + k * 4);
                float4 hv = h4[k];
                s4.x += wv.x * hv.x; s4.y += wv.y * hv.y;
                s4.z += wv.z * hv.z; s4.w += wv.w * hv.w;
            }
            acc += (s4.x + s4.y) + (s4.z + s4.w);
            const float* wy = Wih + (size_t)jj * 272 + 256;
#pragma unroll
            for (int k = 0; k < 4; ++k) {
                float4 wv = *(const float4*)(wy + k * 4);
                acc += wv.x * y_s[4 * k + 0] + wv.y * y_s[4 * k + 1]
                     + wv.z * y_s[4 * k + 2] + wv.w * y_s[4 * k + 3];
            }
            gates[jj] = acc;
        }
        __syncthreads();
        if (tid < DL) {
            float ig = sigf(gates[tid]);
            float fg = sigf(gates[tid + DL]);
            float gg = tanhfast(gates[tid + 2 * DL]);
            float og = sigf(gates[tid + 3 * DL]);
            c = fg * c + ig * gg;
            h_s[tid] = og * tanhfast(c);
        }
        __syncthreads();
        if (tid < 64) {
            // logits + softmax entirely in wave 0. lane = cls*4 + seg
            int cls = tid >> 2, seg = tid & 3;
            float p = 0.f;
            const float* lw = lin_w + cls * DL + seg * 64;
#pragma unroll
            for (int k = 0; k < 16; ++k) {
                float4 wv = *(const float4*)(lw + k * 4);
                float4 hv = h4[seg * 16 + k];
                p += wv.x * hv.x + wv.y * hv.y + wv.z * hv.z + wv.w * hv.w;
            }
            p += __shfl_xor(p, 1);
            p += __shfl_xor(p, 2);
            float logit = p + lin_b[cls];
            float m = logit;
#pragma unroll
            for (int o = 4; o <= 32; o <<= 1) m = fmaxf(m, __shfl_xor(m, o));
            float e = __expf(logit - m);
            float ssum = e;
#pragma unroll
            for (int o = 4; o <= 32; o <<= 1) ssum += __shfl_xor(ssum, o);
            float yv = e / ssum;
            if (seg == 0) {
                y_s[cls] = yv;
                out[((size_t)b * TSEQ + t) * NC + cls] = yv;
            }
        }
        __syncthreads();
    }
}

// ---------------------------------------------------------------------------
extern "C" void kernel_launch(void* const* d_in, const int* in_sizes, int n_in,
                              void* d_out, int out_size, void* d_ws, size_t ws_size,
                              hipStream_t stream)
{
    const float* x     = (const float*)d_in[0];
    const int*   mask  = (const int*)d_in[1];
    const float* Wih_f = (const float*)d_in[2];
    const float* Whh_f = (const float*)d_in[3];
    const float* bih_f = (const float*)d_in[4];
    const float* bhh_f = (const float*)d_in[5];
    const float* Wih_r = (const float*)d_in[6];
    const float* Whh_r = (const float*)d_in[7];
    const float* bih_r = (const float*)d_in[8];
    const float* bhh_r = (const float*)d_in[9];
    const float* fc1_w = (const float*)d_in[10];
    const float* fc2_w = (const float*)d_in[11];
    const float* fc3_w = (const float*)d_in[12];
    const float* fc3_b = (const float*)d_in[13];
    const float* Wih_d = (const float*)d_in[14];
    const float* Whh_d = (const float*)d_in[15];
    const float* bih_d = (const float*)d_in[16];
    const float* bhh_d = (const float*)d_in[17];
    const float* lin_w = (const float*)d_in[18];
    const float* lin_b = (const float*)d_in[19];

    float* ws = (float*)d_ws;
    // layout (floats): Gf[8M] Gr[8M] hs[8M] wat[8M] qp[160K] kp[160K]
    float* Gf   = ws;
    float* Gr   = ws + 8388608;
    float* hs   = ws + 16777216;   // (NB*T, 512) = [h_fwd | h_rev | ctx]
    float* wat  = ws + 25165824;   // attention weights (NB,T,T); later y_enc
    float* qp   = ws + 33554432;
    float* kp   = ws + 33718272;
    float* Gd   = ws;              // reuse Gf+Gr region (16M floats)
    float* yenc = wat;             // reuse wat region after ctx done

    float* outp = (float*)d_out;
    const int M = NB * TSEQ;       // 16384
    dim3 blk(256);

    // 1-2. encoder input projections (biases folded in), time-major outputs
    gemm_nt<1><<<dim3(M / 64, 8), blk, 0, stream>>>(x, DB, Wih_f, DB, bih_f, bhh_f, Gf, 512, 512, DB);
    gemm_nt<2><<<dim3(M / 64, 8), blk, 0, stream>>>(x, DB, Wih_r, DB, bih_r, bhh_r, Gr, 512, 512, DB);
    // 3. bidirectional recurrence
    enc_scan<<<dim3(64), dim3(512), 0, stream>>>(Gf, Gr, Whh_f, Whh_r, hs);
    // 4-5. q/k projections (fc1 split)
    gemm_nt<0><<<dim3(M / 64, 1), blk, 0, stream>>>(hs, 512, fc1_w, 512, nullptr, nullptr, qp, 10, 10, 256);
    gemm_nt<0><<<dim3(M / 64, 1), blk, 0, stream>>>(hs, 512, fc1_w + 256, 512, nullptr, nullptr, kp, 10, 10, 256);
    // 6. attention scores + softmax
    attn_w<<<dim3(M), blk, 0, stream>>>(qp, kp, mask, fc2_w, wat);
    // 7. ctx = w @ hs  (writes hs cols 256:512)
    bgemm_nn<<<dim3(8, 4, NB), blk, 0, stream>>>(wat, hs);
    // 8. y_enc = [hs|ctx] @ fc3^T + b
    gemm_nt<0><<<dim3(M / 64, 4), blk, 0, stream>>>(hs, 512, fc3_w, 512, fc3_b, nullptr, yenc, 256, 256, 512);
    // 9. decoder input projection (cols 0:256 of Wih_d), biases folded, time-major
    gemm_nt<1><<<dim3(M / 64, 16), blk, 0, stream>>>(yenc, 256, Wih_d, 272, bih_d, bhh_d, Gd, 1024, 1024, 256);
    // 10. decoder recurrence + classifier softmax
    dec_scan<<<dim3(NB), dim3(512), 0, stream>>>(Gd, Whh_d, Wih_d, lin_w, lin_b, hs, outp);
}

// Round 2
// 8803.736 us; speedup vs baseline: 1.8839x; 1.8839x over previous
//
#include <hip/hip_runtime.h>

// Problem constants
#define TSEQ 512
#define NB   32     // batch
#define DB   768    // d_bert
#define H2E  128    // encoder hidden per dir
#define DL   256    // d_lstm
#define NC   16     // n_class

__device__ __forceinline__ float sigf(float x) { return 1.0f / (1.0f + __expf(-x)); }
__device__ __forceinline__ float tanhfast(float x) { return 1.0f - 2.0f / (1.0f + __expf(2.0f * x)); }

// ---------------------------------------------------------------------------
// Generic f32 GEMM: C[remap(m), n] = sum_k A[m,k]*W[n,k] + b1[n] + b2[n]
// 64x64 tile, BK=16, 256 threads, 4x4 microtile.
// MODE 0: direct rows. MODE 1: m=b*T+t -> out row t*NB+b. MODE 2: -> (T-1-t)*NB+b.
// ---------------------------------------------------------------------------
template <int MODE>
__global__ __launch_bounds__(256) void gemm_nt(
    const float* __restrict__ A, int lda,
    const float* __restrict__ W, int ldw,
    const float* __restrict__ b1, const float* __restrict__ b2,
    float* __restrict__ C, int ldc, int N, int K)
{
    __shared__ float As[16][68];
    __shared__ float Ws[16][68];
    const int tid = threadIdx.x;
    const int m0 = blockIdx.x * 64;
    const int n0 = blockIdx.y * 64;
    const int tx = tid & 15, ty = tid >> 4;
    const int lrow = tid >> 2;
    const int lk = (tid & 3) * 4;
    float acc[4][4] = {};

    for (int k0 = 0; k0 < K; k0 += 16) {
        float4 av = *(const float4*)(A + (size_t)(m0 + lrow) * lda + k0 + lk);
        float4 wv = make_float4(0.f, 0.f, 0.f, 0.f);
        if (n0 + lrow < N)
            wv = *(const float4*)(W + (size_t)(n0 + lrow) * ldw + k0 + lk);
        As[lk + 0][lrow] = av.x; As[lk + 1][lrow] = av.y;
        As[lk + 2][lrow] = av.z; As[lk + 3][lrow] = av.w;
        Ws[lk + 0][lrow] = wv.x; Ws[lk + 1][lrow] = wv.y;
        Ws[lk + 2][lrow] = wv.z; Ws[lk + 3][lrow] = wv.w;
        __syncthreads();
#pragma unroll
        for (int kk = 0; kk < 16; ++kk) {
            float a0 = As[kk][ty * 4 + 0], a1 = As[kk][ty * 4 + 1];
            float a2 = As[kk][ty * 4 + 2], a3 = As[kk][ty * 4 + 3];
            float w0 = Ws[kk][tx * 4 + 0], w1 = Ws[kk][tx * 4 + 1];
            float w2 = Ws[kk][tx * 4 + 2], w3 = Ws[kk][tx * 4 + 3];
            acc[0][0] += a0 * w0; acc[0][1] += a0 * w1; acc[0][2] += a0 * w2; acc[0][3] += a0 * w3;
            acc[1][0] += a1 * w0; acc[1][1] += a1 * w1; acc[1][2] += a1 * w2; acc[1][3] += a1 * w3;
            acc[2][0] += a2 * w0; acc[2][1] += a2 * w1; acc[2][2] += a2 * w2; acc[2][3] += a2 * w3;
            acc[3][0] += a3 * w0; acc[3][1] += a3 * w1; acc[3][2] += a3 * w2; acc[3][3] += a3 * w3;
        }
        __syncthreads();
    }

#pragma unroll
    for (int i = 0; i < 4; ++i) {
        int gm = m0 + ty * 4 + i;
        int orow;
        if (MODE == 0) orow = gm;
        else {
            int bb = gm >> 9;          // /TSEQ
            int tt = gm & (TSEQ - 1);
            orow = (MODE == 1 ? tt : (TSEQ - 1 - tt)) * NB + bb;
        }
#pragma unroll
        for (int j = 0; j < 4; ++j) {
            int gn = n0 + tx * 4 + j;
            if (gn < N) {
                float bias = (b1 ? b1[gn] : 0.f) + (b2 ? b2[gn] : 0.f);
                C[(size_t)orow * ldc + gn] = acc[i][j] + bias;
            }
        }
    }
}

// ---------------------------------------------------------------------------
// Encoder LSTM scan (unchanged this round).
// ---------------------------------------------------------------------------
__global__ __launch_bounds__(512) void enc_scan(
    const float* __restrict__ Gf, const float* __restrict__ Gr,
    const float* __restrict__ Whh_f, const float* __restrict__ Whh_r,
    float* __restrict__ hs_ctx)
{
    const int dir = blockIdx.x & 1;
    const int b = blockIdx.x >> 1;
    const float* __restrict__ G = dir ? Gr : Gf;
    const float* __restrict__ Whh = dir ? Whh_r : Whh_f;
    const int j = threadIdx.x;   // gate 0..511

    __shared__ float4 h4[H2E / 4];
    __shared__ float gates[4 * H2E];
    float* h_s = (float*)h4;

    float4 w[32];
#pragma unroll
    for (int k = 0; k < 32; ++k)
        w[k] = *(const float4*)(Whh + (size_t)j * H2E + k * 4);

    float c = 0.f;
    if (j < H2E) h_s[j] = 0.f;
    __syncthreads();

    for (int t = 0; t < TSEQ; ++t) {
        const float* grow = G + ((size_t)t * NB + b) * 512;
        float acc = grow[j];
#pragma unroll
        for (int k = 0; k < 32; ++k) {
            float4 hv = h4[k];
            acc += w[k].x * hv.x + w[k].y * hv.y + w[k].z * hv.z + w[k].w * hv.w;
        }
        gates[j] = acc;
        __syncthreads();
        if (j < H2E) {
            float ig = sigf(gates[j]);
            float fg = sigf(gates[j + H2E]);
            float gg = tanhfast(gates[j + 2 * H2E]);
            float og = sigf(gates[j + 3 * H2E]);
            c = fg * c + ig * gg;
            float h = og * tanhfast(c);
            h_s[j] = h;
            int tout = dir ? (TSEQ - 1 - t) : t;
            hs_ctx[((size_t)b * TSEQ + tout) * 512 + dir * H2E + j] = h;
        }
        __syncthreads();
    }
}

// ---------------------------------------------------------------------------
// Fused additive-attention scores + softmax (unchanged).
// ---------------------------------------------------------------------------
__global__ __launch_bounds__(256) void attn_w(
    const float* __restrict__ qp, const float* __restrict__ kp,
    const int* __restrict__ mask, const float* __restrict__ fc2,
    float* __restrict__ wout)
{
    const int bi = blockIdx.x;       // b*T + i
    const int b = bi >> 9;
    const int tid = threadIdx.x;
    __shared__ float kps[TSEQ * 11];
    __shared__ float red[8];

    const float* kpb = kp + (size_t)b * TSEQ * 10;
    for (int idx = tid; idx < TSEQ * 10; idx += 256) {
        int j = idx / 10, xx = idx - j * 10;
        kps[j * 11 + xx] = kpb[idx];
    }
    float q[10], vv[10];
#pragma unroll
    for (int xx = 0; xx < 10; ++xx) {
        q[xx] = qp[(size_t)bi * 10 + xx];
        vv[xx] = fc2[xx];
    }
    __syncthreads();

    float a[2];
#pragma unroll
    for (int jj = 0; jj < 2; ++jj) {
        int j = tid + jj * 256;
        float s = 0.f;
#pragma unroll
        for (int xx = 0; xx < 10; ++xx)
            s += vv[xx] * tanhfast(q[xx] + kps[j * 11 + xx]);
        if (mask[(size_t)b * TSEQ + j] == 0) s = -1e30f;
        a[jj] = s;
    }

    float m = fmaxf(a[0], a[1]);
#pragma unroll
    for (int o = 32; o >= 1; o >>= 1) m = fmaxf(m, __shfl_xor(m, o));
    if ((tid & 63) == 0) red[tid >> 6] = m;
    __syncthreads();
    m = fmaxf(fmaxf(red[0], red[1]), fmaxf(red[2], red[3]));

    float e0 = __expf(a[0] - m), e1 = __expf(a[1] - m);
    float s = e0 + e1;
#pragma unroll
    for (int o = 32; o >= 1; o >>= 1) s += __shfl_xor(s, o);
    if ((tid & 63) == 0) red[4 + (tid >> 6)] = s;
    __syncthreads();
    s = (red[4] + red[5]) + (red[6] + red[7]);
    float inv = 1.0f / s;
    wout[(size_t)bi * TSEQ + tid] = e0 * inv;
    wout[(size_t)bi * TSEQ + tid + 256] = e1 * inv;
}

// ---------------------------------------------------------------------------
// Batched NN GEMM: ctx = w @ hs (unchanged).
// ---------------------------------------------------------------------------
__global__ __launch_bounds__(256) void bgemm_nn(
    const float* __restrict__ Wmat,  // (NB, T, T)
    float* __restrict__ hs_ctx)      // (NB*T, 512): read cols [0,256), write [256,512)
{
    __shared__ float As[16][68];
    __shared__ float Bs[16][68];
    const int tid = threadIdx.x;
    const int b = blockIdx.z;
    const int i0 = blockIdx.x * 64;
    const int d0 = blockIdx.y * 64;
    const int tx = tid & 15, ty = tid >> 4;
    float acc[4][4] = {};
    const float* Ab = Wmat + (size_t)b * TSEQ * TSEQ;
    const float* Bb = hs_ctx + (size_t)b * TSEQ * 512;

    for (int k0 = 0; k0 < TSEQ; k0 += 16) {
        {
            int r = tid >> 2, kq = (tid & 3) * 4;
            float4 v = *(const float4*)(Ab + (size_t)(i0 + r) * TSEQ + k0 + kq);
            As[kq + 0][r] = v.x; As[kq + 1][r] = v.y; As[kq + 2][r] = v.z; As[kq + 3][r] = v.w;
        }
        {
            int kk = tid >> 4, dq = (tid & 15) * 4;
            float4 v = *(const float4*)(Bb + (size_t)(k0 + kk) * 512 + d0 + dq);
            *(float4*)&Bs[kk][dq] = v;
        }
        __syncthreads();
#pragma unroll
        for (int kk = 0; kk < 16; ++kk) {
            float a0 = As[kk][ty * 4 + 0], a1 = As[kk][ty * 4 + 1];
            float a2 = As[kk][ty * 4 + 2], a3 = As[kk][ty * 4 + 3];
            float b0 = Bs[kk][tx * 4 + 0], b1 = Bs[kk][tx * 4 + 1];
            float b2 = Bs[kk][tx * 4 + 2], b3 = Bs[kk][tx * 4 + 3];
            acc[0][0] += a0 * b0; acc[0][1] += a0 * b1; acc[0][2] += a0 * b2; acc[0][3] += a0 * b3;
            acc[1][0] += a1 * b0; acc[1][1] += a1 * b1; acc[1][2] += a1 * b2; acc[1][3] += a1 * b3;
            acc[2][0] += a2 * b0; acc[2][1] += a2 * b1; acc[2][2] += a2 * b2; acc[2][3] += a2 * b3;
            acc[3][0] += a3 * b0; acc[3][1] += a3 * b1; acc[3][2] += a3 * b2; acc[3][3] += a3 * b3;
        }
        __syncthreads();
    }
#pragma unroll
    for (int i = 0; i < 4; ++i)
#pragma unroll
        for (int j = 0; j < 4; ++j)
            hs_ctx[((size_t)b * TSEQ + i0 + ty * 4 + i) * 512 + 256 + d0 + tx * 4 + j] = acc[i][j];
}

// ---------------------------------------------------------------------------
// Decoder init: h(-1) = hs[:, T-1, :DL] into hbuf[0]; zero the 128 flags.
// ---------------------------------------------------------------------------
__global__ __launch_bounds__(256) void dec_init(
    const float* __restrict__ hs_ctx, float* hbuf, int* flags)
{
    const int tid = threadIdx.x;
    if (tid < 128)
        __hip_atomic_store(&flags[tid], 0, __ATOMIC_RELAXED, __HIP_MEMORY_SCOPE_AGENT);
    for (int i = tid; i < NB * DL; i += 256) {
        int bb = i >> 8, u = i & 255;
        float v = hs_ctx[((size_t)bb * TSEQ + (TSEQ - 1)) * 512 + u];
        __hip_atomic_store(&hbuf[i], v, __ATOMIC_RELAXED, __HIP_MEMORY_SCOPE_AGENT);
    }
}

// ---------------------------------------------------------------------------
// Decoder scan v2: weight-stationary, 128 persistent blocks (16 row-groups x
// 8 batch-groups), flag-barrier per step, double-buffered h state in global.
// Block (rg,bg): units [rg*16, rg*16+16) x batches [bg*4, bg*4+4).
// Weight slice (64 rows x 256) lives in LDS for all 512 steps.
// ---------------------------------------------------------------------------
__global__ __launch_bounds__(256) void dec_scan2(
    const float* __restrict__ Gd,     // (T, NB, 1024), biases folded
    const float* __restrict__ Whh,    // (1024, 256)
    const float* __restrict__ Wih,    // (1024, 272); cols 256:272 multiply y
    const float* __restrict__ lin_w,  // (16, 256)
    const float* __restrict__ lin_b,  // (16,)
    float* hbuf,                      // (2, NB, DL)
    int* flags,                       // (128,)
    float* __restrict__ out)          // (NB, T, NC)
{
    const int tid = threadIdx.x;
    const int rg = blockIdx.x & 15;
    const int bg = blockIdx.x >> 4;
    const int blk = blockIdx.x;

    __shared__ float Wlds[64][260];    // 64 gate rows x 256 (padded)
    __shared__ float Wylds[64][17];    // y-term weights
    __shared__ float linlds[16][257];  // lin_w
    __shared__ float hlds[4][260];     // h(t-1) for 4 batches
    __shared__ float ylds[4][17];      // y(t-1)
    __shared__ float glds[4][65];      // gate exchange

    const int rr_t = tid >> 2;         // local gate row 0..63
    const int bb_t = tid & 3;          // local batch 0..3
    // local row -> global gate row: q*256 + rg*16 + u
    const int jrow = ((rr_t >> 4) << 8) + rg * 16 + (rr_t & 15);

    // ---- stage weights (once) ----
    for (int i = tid; i < 64 * 64; i += 256) {
        int rr = i >> 6, k4 = (i & 63) * 4;
        int j = ((rr >> 4) << 8) + rg * 16 + (rr & 15);
        *(float4*)&Wlds[rr][k4] = *(const float4*)(Whh + (size_t)j * 256 + k4);
    }
    {
        int rr = tid >> 2, c4 = (tid & 3) * 4;
        int j = ((rr >> 4) << 8) + rg * 16 + (rr & 15);
        *(float4*)&Wylds[rr][c4] = *(const float4*)(Wih + (size_t)j * 272 + 256 + c4);
    }
    for (int i = tid; i < 16 * 64; i += 256) {
        int r = i >> 6, k4 = (i & 63) * 4;
        *(float4*)&linlds[r][k4] = *(const float4*)(lin_w + r * 256 + k4);
    }
    const float lb = lin_b[tid & 15];
    float cstate = 0.f;
    __syncthreads();

    for (int t = 0; t <= TSEQ; ++t) {
        // prefetch this step's Gd value (independent of h) before the wait
        float gval = 0.f;
        if (t < TSEQ)
            gval = Gd[((size_t)t * NB + bg * 4 + bb_t) * 1024 + jrow];

        // barrier: all blocks have published h(t-1)
        if (t > 0) {
            if (tid < 128) {
                while (__hip_atomic_load(&flags[tid], __ATOMIC_ACQUIRE,
                                         __HIP_MEMORY_SCOPE_AGENT) < t)
                    __builtin_amdgcn_s_sleep(1);
            }
        }
        __syncthreads();

        // load h(t-1) for our 4 batches
        const float* hsrc = hbuf + (size_t)(t & 1) * (NB * DL) + (size_t)bg * 4 * DL;
        for (int i = tid; i < 4 * DL; i += 256)
            hlds[i >> 8][i & 255] =
                __hip_atomic_load(&hsrc[i], __ATOMIC_RELAXED, __HIP_MEMORY_SCOPE_AGENT);
        __syncthreads();

        // y(t-1) = softmax(lin_w @ h(t-1) + lin_b) (redundant per block); y(-1)=0
        if (tid < 64) {
            int bb = tid >> 4, cls = tid & 15;
            float yv;
            if (t == 0) {
                yv = 0.f;
            } else {
                float p = 0.f;
#pragma unroll 16
                for (int k = 0; k < 256; k += 4)
                    p += linlds[cls][k] * hlds[bb][k] + linlds[cls][k + 1] * hlds[bb][k + 1]
                       + linlds[cls][k + 2] * hlds[bb][k + 2] + linlds[cls][k + 3] * hlds[bb][k + 3];
                float logit = p + lb;
                float m = logit;
#pragma unroll
                for (int o = 1; o < 16; o <<= 1) m = fmaxf(m, __shfl_xor(m, o, 16));
                float e = __expf(logit - m);
                float ss = e;
#pragma unroll
                for (int o = 1; o < 16; o <<= 1) ss += __shfl_xor(ss, o, 16);
                yv = e / ss;
            }
            ylds[bb][cls] = yv;
            if (t > 0 && rg == 0)
                out[(((size_t)(bg * 4 + bb)) * TSEQ + (t - 1)) * NC + cls] = yv;
        }
        __syncthreads();

        if (t == TSEQ) break;   // uniform across block

        // gates: Gd + Whh·h + Wy·y
        {
            float acc = gval;
            const float4* wrow = (const float4*)&Wlds[rr_t][0];
            const float4* hrow = (const float4*)&hlds[bb_t][0];
#pragma unroll 8
            for (int k4 = 0; k4 < 64; ++k4) {
                float4 w = wrow[k4], h = hrow[k4];
                acc += w.x * h.x + w.y * h.y + w.z * h.z + w.w * h.w;
            }
#pragma unroll
            for (int c = 0; c < 16; ++c)
                acc += Wylds[rr_t][c] * ylds[bb_t][c];
            glds[bb_t][rr_t] = acc;
        }
        __syncthreads();

        // c,h update + publish
        if (tid < 64) {
            int bb = tid >> 4, u = tid & 15;
            float ig = sigf(glds[bb][u]);
            float fg = sigf(glds[bb][16 + u]);
            float gg = tanhfast(glds[bb][32 + u]);
            float og = sigf(glds[bb][48 + u]);
            cstate = fg * cstate + ig * gg;
            float h = og * tanhfast(cstate);
            float* hdst = hbuf + (size_t)((t + 1) & 1) * (NB * DL)
                        + (size_t)(bg * 4 + bb) * DL + rg * 16 + u;
            __hip_atomic_store(hdst, h, __ATOMIC_RELAXED, __HIP_MEMORY_SCOPE_AGENT);
        }
        __syncthreads();
        if (tid == 0) {
            __threadfence();
            __hip_atomic_store(&flags[blk], t + 1, __ATOMIC_RELEASE,
                               __HIP_MEMORY_SCOPE_AGENT);
        }
    }
}

// ---------------------------------------------------------------------------
extern "C" void kernel_launch(void* const* d_in, const int* in_sizes, int n_in,
                              void* d_out, int out_size, void* d_ws, size_t ws_size,
                              hipStream_t stream)
{
    const float* x     = (const float*)d_in[0];
    const int*   mask  = (const int*)d_in[1];
    const float* Wih_f = (const float*)d_in[2];
    const float* Whh_f = (const float*)d_in[3];
    const float* bih_f = (const float*)d_in[4];
    const float* bhh_f = (const float*)d_in[5];
    const float* Wih_r = (const float*)d_in[6];
    const float* Whh_r = (const float*)d_in[7];
    const float* bih_r = (const float*)d_in[8];
    const float* bhh_r = (const float*)d_in[9];
    const float* fc1_w = (const float*)d_in[10];
    const float* fc2_w = (const float*)d_in[11];
    const float* fc3_w = (const float*)d_in[12];
    const float* fc3_b = (const float*)d_in[13];
    const float* Wih_d = (const float*)d_in[14];
    const float* Whh_d = (const float*)d_in[15];
    const float* bih_d = (const float*)d_in[16];
    const float* bhh_d = (const float*)d_in[17];
    const float* lin_w = (const float*)d_in[18];
    const float* lin_b = (const float*)d_in[19];

    float* ws = (float*)d_ws;
    // layout (floats): Gf[8M] Gr[8M] hs[8M] wat[8M] qp[160K] kp[160K]
    float* Gf   = ws;
    float* Gr   = ws + 8388608;
    float* hs   = ws + 16777216;   // (NB*T, 512) = [h_fwd | h_rev | ctx]
    float* wat  = ws + 25165824;   // attention weights (NB,T,T); later y_enc
    float* qp   = ws + 33554432;
    float* kp   = ws + 33718272;
    float* Gd   = ws;              // reuse Gf+Gr region (16M floats)
    float* yenc = wat;             // reuse wat region: yenc = wat[0 : 4M)
    float* hbuf = wat + 4194304;   // dead upper half of wat after kernel 7
    int*   flags = (int*)(wat + 4194304 + 2 * NB * DL);

    float* outp = (float*)d_out;
    const int M = NB * TSEQ;       // 16384
    dim3 blk(256);

    // 1-2. encoder input projections (biases folded in), time-major outputs
    gemm_nt<1><<<dim3(M / 64, 8), blk, 0, stream>>>(x, DB, Wih_f, DB, bih_f, bhh_f, Gf, 512, 512, DB);
    gemm_nt<2><<<dim3(M / 64, 8), blk, 0, stream>>>(x, DB, Wih_r, DB, bih_r, bhh_r, Gr, 512, 512, DB);
    // 3. bidirectional recurrence
    enc_scan<<<dim3(64), dim3(512), 0, stream>>>(Gf, Gr, Whh_f, Whh_r, hs);
    // 4-5. q/k projections (fc1 split)
    gemm_nt<0><<<dim3(M / 64, 1), blk, 0, stream>>>(hs, 512, fc1_w, 512, nullptr, nullptr, qp, 10, 10, 256);
    gemm_nt<0><<<dim3(M / 64, 1), blk, 0, stream>>>(hs, 512, fc1_w + 256, 512, nullptr, nullptr, kp, 10, 10, 256);
    // 6. attention scores + softmax
    attn_w<<<dim3(M), blk, 0, stream>>>(qp, kp, mask, fc2_w, wat);
    // 7. ctx = w @ hs  (writes hs cols 256:512)
    bgemm_nn<<<dim3(8, 4, NB), blk, 0, stream>>>(wat, hs);
    // 8. y_enc = [hs|ctx] @ fc3^T + b   (into wat[0:4M))
    gemm_nt<0><<<dim3(M / 64, 4), blk, 0, stream>>>(hs, 512, fc3_w, 512, fc3_b, nullptr, yenc, 256, 256, 512);
    // 8.5 decoder state init (after wat's attention use is done)
    dec_init<<<dim3(1), blk, 0, stream>>>(hs, hbuf, flags);
    // 9. decoder input projection, biases folded, time-major
    gemm_nt<1><<<dim3(M / 64, 16), blk, 0, stream>>>(yenc, 256, Wih_d, 272, bih_d, bhh_d, Gd, 1024, 1024, 256);
    // 10. decoder recurrence + classifier softmax (weight-stationary, flag barrier)
    dec_scan2<<<dim3(128), blk, 0, stream>>>(Gd, Whh_d, Wih_d, lin_w, lin_b, hbuf, flags, outp);
}

// Round 3
// 4863.397 us; speedup vs baseline: 3.4103x; 1.8102x over previous
//
#include <hip/hip_runtime.h>

// Problem constants
#define TSEQ 512
#define NB   32     // batch
#define DB   768    // d_bert
#define H2E  128    // encoder hidden per dir
#define DL   256    // d_lstm
#define NC   16     // n_class

__device__ __forceinline__ float sigf(float x) { return 1.0f / (1.0f + __expf(-x)); }
__device__ __forceinline__ float tanhfast(float x) { return 1.0f - 2.0f / (1.0f + __expf(2.0f * x)); }

// ---------------------------------------------------------------------------
// Generic f32 GEMM: C[remap(m), n] = sum_k A[m,k]*W[n,k] + b1[n] + b2[n]
// 64x64 tile, BK=16, 256 threads, 4x4 microtile.
// MODE 0: direct rows. MODE 1: m=b*T+t -> out row t*NB+b. MODE 2: -> (T-1-t)*NB+b.
// ---------------------------------------------------------------------------
template <int MODE>
__global__ __launch_bounds__(256) void gemm_nt(
    const float* __restrict__ A, int lda,
    const float* __restrict__ W, int ldw,
    const float* __restrict__ b1, const float* __restrict__ b2,
    float* __restrict__ C, int ldc, int N, int K)
{
    __shared__ float As[16][68];
    __shared__ float Ws[16][68];
    const int tid = threadIdx.x;
    const int m0 = blockIdx.x * 64;
    const int n0 = blockIdx.y * 64;
    const int tx = tid & 15, ty = tid >> 4;
    const int lrow = tid >> 2;
    const int lk = (tid & 3) * 4;
    float acc[4][4] = {};

    for (int k0 = 0; k0 < K; k0 += 16) {
        float4 av = *(const float4*)(A + (size_t)(m0 + lrow) * lda + k0 + lk);
        float4 wv = make_float4(0.f, 0.f, 0.f, 0.f);
        if (n0 + lrow < N)
            wv = *(const float4*)(W + (size_t)(n0 + lrow) * ldw + k0 + lk);
        As[lk + 0][lrow] = av.x; As[lk + 1][lrow] = av.y;
        As[lk + 2][lrow] = av.z; As[lk + 3][lrow] = av.w;
        Ws[lk + 0][lrow] = wv.x; Ws[lk + 1][lrow] = wv.y;
        Ws[lk + 2][lrow] = wv.z; Ws[lk + 3][lrow] = wv.w;
        __syncthreads();
#pragma unroll
        for (int kk = 0; kk < 16; ++kk) {
            float a0 = As[kk][ty * 4 + 0], a1 = As[kk][ty * 4 + 1];
            float a2 = As[kk][ty * 4 + 2], a3 = As[kk][ty * 4 + 3];
            float w0 = Ws[kk][tx * 4 + 0], w1 = Ws[kk][tx * 4 + 1];
            float w2 = Ws[kk][tx * 4 + 2], w3 = Ws[kk][tx * 4 + 3];
            acc[0][0] += a0 * w0; acc[0][1] += a0 * w1; acc[0][2] += a0 * w2; acc[0][3] += a0 * w3;
            acc[1][0] += a1 * w0; acc[1][1] += a1 * w1; acc[1][2] += a1 * w2; acc[1][3] += a1 * w3;
            acc[2][0] += a2 * w0; acc[2][1] += a2 * w1; acc[2][2] += a2 * w2; acc[2][3] += a2 * w3;
            acc[3][0] += a3 * w0; acc[3][1] += a3 * w1; acc[3][2] += a3 * w2; acc[3][3] += a3 * w3;
        }
        __syncthreads();
    }

#pragma unroll
    for (int i = 0; i < 4; ++i) {
        int gm = m0 + ty * 4 + i;
        int orow;
        if (MODE == 0) orow = gm;
        else {
            int bb = gm >> 9;          // /TSEQ
            int tt = gm & (TSEQ - 1);
            orow = (MODE == 1 ? tt : (TSEQ - 1 - tt)) * NB + bb;
        }
#pragma unroll
        for (int j = 0; j < 4; ++j) {
            int gn = n0 + tx * 4 + j;
            if (gn < N) {
                float bias = (b1 ? b1[gn] : 0.f) + (b2 ? b2[gn] : 0.f);
                C[(size_t)orow * ldc + gn] = acc[i][j] + bias;
            }
        }
    }
}

// ---------------------------------------------------------------------------
// Encoder LSTM scan (unchanged this round).
// ---------------------------------------------------------------------------
__global__ __launch_bounds__(512) void enc_scan(
    const float* __restrict__ Gf, const float* __restrict__ Gr,
    const float* __restrict__ Whh_f, const float* __restrict__ Whh_r,
    float* __restrict__ hs_ctx)
{
    const int dir = blockIdx.x & 1;
    const int b = blockIdx.x >> 1;
    const float* __restrict__ G = dir ? Gr : Gf;
    const float* __restrict__ Whh = dir ? Whh_r : Whh_f;
    const int j = threadIdx.x;   // gate 0..511

    __shared__ float4 h4[H2E / 4];
    __shared__ float gates[4 * H2E];
    float* h_s = (float*)h4;

    float4 w[32];
#pragma unroll
    for (int k = 0; k < 32; ++k)
        w[k] = *(const float4*)(Whh + (size_t)j * H2E + k * 4);

    float c = 0.f;
    if (j < H2E) h_s[j] = 0.f;
    __syncthreads();

    for (int t = 0; t < TSEQ; ++t) {
        const float* grow = G + ((size_t)t * NB + b) * 512;
        float acc = grow[j];
#pragma unroll
        for (int k = 0; k < 32; ++k) {
            float4 hv = h4[k];
            acc += w[k].x * hv.x + w[k].y * hv.y + w[k].z * hv.z + w[k].w * hv.w;
        }
        gates[j] = acc;
        __syncthreads();
        if (j < H2E) {
            float ig = sigf(gates[j]);
            float fg = sigf(gates[j + H2E]);
            float gg = tanhfast(gates[j + 2 * H2E]);
            float og = sigf(gates[j + 3 * H2E]);
            c = fg * c + ig * gg;
            float h = og * tanhfast(c);
            h_s[j] = h;
            int tout = dir ? (TSEQ - 1 - t) : t;
            hs_ctx[((size_t)b * TSEQ + tout) * 512 + dir * H2E + j] = h;
        }
        __syncthreads();
    }
}

// ---------------------------------------------------------------------------
// Fused additive-attention scores + softmax (unchanged).
// ---------------------------------------------------------------------------
__global__ __launch_bounds__(256) void attn_w(
    const float* __restrict__ qp, const float* __restrict__ kp,
    const int* __restrict__ mask, const float* __restrict__ fc2,
    float* __restrict__ wout)
{
    const int bi = blockIdx.x;       // b*T + i
    const int b = bi >> 9;
    const int tid = threadIdx.x;
    __shared__ float kps[TSEQ * 11];
    __shared__ float red[8];

    const float* kpb = kp + (size_t)b * TSEQ * 10;
    for (int idx = tid; idx < TSEQ * 10; idx += 256) {
        int j = idx / 10, xx = idx - j * 10;
        kps[j * 11 + xx] = kpb[idx];
    }
    float q[10], vv[10];
#pragma unroll
    for (int xx = 0; xx < 10; ++xx) {
        q[xx] = qp[(size_t)bi * 10 + xx];
        vv[xx] = fc2[xx];
    }
    __syncthreads();

    float a[2];
#pragma unroll
    for (int jj = 0; jj < 2; ++jj) {
        int j = tid + jj * 256;
        float s = 0.f;
#pragma unroll
        for (int xx = 0; xx < 10; ++xx)
            s += vv[xx] * tanhfast(q[xx] + kps[j * 11 + xx]);
        if (mask[(size_t)b * TSEQ + j] == 0) s = -1e30f;
        a[jj] = s;
    }

    float m = fmaxf(a[0], a[1]);
#pragma unroll
    for (int o = 32; o >= 1; o >>= 1) m = fmaxf(m, __shfl_xor(m, o));
    if ((tid & 63) == 0) red[tid >> 6] = m;
    __syncthreads();
    m = fmaxf(fmaxf(red[0], red[1]), fmaxf(red[2], red[3]));

    float e0 = __expf(a[0] - m), e1 = __expf(a[1] - m);
    float s = e0 + e1;
#pragma unroll
    for (int o = 32; o >= 1; o >>= 1) s += __shfl_xor(s, o);
    if ((tid & 63) == 0) red[4 + (tid >> 6)] = s;
    __syncthreads();
    s = (red[4] + red[5]) + (red[6] + red[7]);
    float inv = 1.0f / s;
    wout[(size_t)bi * TSEQ + tid] = e0 * inv;
    wout[(size_t)bi * TSEQ + tid + 256] = e1 * inv;
}

// ---------------------------------------------------------------------------
// Batched NN GEMM: ctx = w @ hs (unchanged).
// ---------------------------------------------------------------------------
__global__ __launch_bounds__(256) void bgemm_nn(
    const float* __restrict__ Wmat,  // (NB, T, T)
    float* __restrict__ hs_ctx)      // (NB*T, 512): read cols [0,256), write [256,512)
{
    __shared__ float As[16][68];
    __shared__ float Bs[16][68];
    const int tid = threadIdx.x;
    const int b = blockIdx.z;
    const int i0 = blockIdx.x * 64;
    const int d0 = blockIdx.y * 64;
    const int tx = tid & 15, ty = tid >> 4;
    float acc[4][4] = {};
    const float* Ab = Wmat + (size_t)b * TSEQ * TSEQ;
    const float* Bb = hs_ctx + (size_t)b * TSEQ * 512;

    for (int k0 = 0; k0 < TSEQ; k0 += 16) {
        {
            int r = tid >> 2, kq = (tid & 3) * 4;
            float4 v = *(const float4*)(Ab + (size_t)(i0 + r) * TSEQ + k0 + kq);
            As[kq + 0][r] = v.x; As[kq + 1][r] = v.y; As[kq + 2][r] = v.z; As[kq + 3][r] = v.w;
        }
        {
            int kk = tid >> 4, dq = (tid & 15) * 4;
            float4 v = *(const float4*)(Bb + (size_t)(k0 + kk) * 512 + d0 + dq);
            *(float4*)&Bs[kk][dq] = v;
        }
        __syncthreads();
#pragma unroll
        for (int kk = 0; kk < 16; ++kk) {
            float a0 = As[kk][ty * 4 + 0], a1 = As[kk][ty * 4 + 1];
            float a2 = As[kk][ty * 4 + 2], a3 = As[kk][ty * 4 + 3];
            float b0 = Bs[kk][tx * 4 + 0], b1 = Bs[kk][tx * 4 + 1];
            float b2 = Bs[kk][tx * 4 + 2], b3 = Bs[kk][tx * 4 + 3];
            acc[0][0] += a0 * b0; acc[0][1] += a0 * b1; acc[0][2] += a0 * b2; acc[0][3] += a0 * b3;
            acc[1][0] += a1 * b0; acc[1][1] += a1 * b1; acc[1][2] += a1 * b2; acc[1][3] += a1 * b3;
            acc[2][0] += a2 * b0; acc[2][1] += a2 * b1; acc[2][2] += a2 * b2; acc[2][3] += a2 * b3;
            acc[3][0] += a3 * b0; acc[3][1] += a3 * b1; acc[3][2] += a3 * b2; acc[3][3] += a3 * b3;
        }
        __syncthreads();
    }
#pragma unroll
    for (int i = 0; i < 4; ++i)
#pragma unroll
        for (int j = 0; j < 4; ++j)
            hs_ctx[((size_t)b * TSEQ + i0 + ty * 4 + i) * 512 + 256 + d0 + tx * 4 + j] = acc[i][j];
}

// ---------------------------------------------------------------------------
// Decoder init: h(-1) = hs[:, T-1, :DL] into hbuf[0]; zero the 128 flags.
// ---------------------------------------------------------------------------
__global__ __launch_bounds__(256) void dec_init(
    const float* __restrict__ hs_ctx, float* hbuf, int* flags)
{
    const int tid = threadIdx.x;
    if (tid < 128)
        __hip_atomic_store(&flags[tid], 0, __ATOMIC_RELAXED, __HIP_MEMORY_SCOPE_AGENT);
    for (int i = tid; i < NB * DL; i += 256) {
        int bb = i >> 8, u = i & 255;
        float v = hs_ctx[((size_t)bb * TSEQ + (TSEQ - 1)) * 512 + u];
        __hip_atomic_store(&hbuf[i], v, __ATOMIC_RELAXED, __HIP_MEMORY_SCOPE_AGENT);
    }
}

// ---------------------------------------------------------------------------
// Decoder scan v3: weight-stationary, 128 persistent blocks (16 row-groups x
// 8 batch-groups). ALL cross-block traffic via RELAXED agent atomics (bypass
// L2 to the coherent L3) -- no acquire/release, so no buffer_inv/wbl2 storms.
// Ordering: writer does h-stores -> __syncthreads (drains vmcnt) -> flag store;
// reader spins on flags -> __syncthreads -> h loads.
// Each block polls only its own batch-group's 16 flags (groups independent).
// ---------------------------------------------------------------------------
__global__ __launch_bounds__(256) void dec_scan2(
    const float* __restrict__ Gd,     // (T, NB, 1024), biases folded
    const float* __restrict__ Whh,    // (1024, 256)
    const float* __restrict__ Wih,    // (1024, 272); cols 256:272 multiply y
    const float* __restrict__ lin_w,  // (16, 256)
    const float* __restrict__ lin_b,  // (16,)
    float* hbuf,                      // (2, NB, DL)
    int* flags,                       // (128,)
    float* __restrict__ out)          // (NB, T, NC)
{
    const int tid = threadIdx.x;
    const int rg = blockIdx.x & 15;
    const int bg = blockIdx.x >> 4;
    const int blk = blockIdx.x;

    __shared__ float Wlds[64][260];    // 64 gate rows x 256 (padded)
    __shared__ float Wylds[64][17];    // y-term weights
    __shared__ float linlds[16][257];  // lin_w
    __shared__ float hlds[4][260];     // h(t-1) for 4 batches
    __shared__ float ylds[4][17];      // y(t-1)
    __shared__ float glds[4][65];      // gate exchange

    const int rr_t = tid >> 2;         // local gate row 0..63
    const int bb_t = tid & 3;          // local batch 0..3
    // local row -> global gate row: q*256 + rg*16 + u
    const int jrow = ((rr_t >> 4) << 8) + rg * 16 + (rr_t & 15);

    // y-softmax thread mapping: wave = batch, lane = cls*4 + seg
    const int y_bb  = tid >> 6;
    const int y_cls = (tid >> 2) & 15;
    const int y_seg = tid & 3;
    const float lb = lin_b[y_cls];

    // ---- stage weights (once) ----
    for (int i = tid; i < 64 * 64; i += 256) {
        int rr = i >> 6, k4 = (i & 63) * 4;
        int j = ((rr >> 4) << 8) + rg * 16 + (rr & 15);
        *(float4*)&Wlds[rr][k4] = *(const float4*)(Whh + (size_t)j * 256 + k4);
    }
    {
        int rr = tid >> 2, c4 = (tid & 3) * 4;
        int j = ((rr >> 4) << 8) + rg * 16 + (rr & 15);
        *(float4*)&Wylds[rr][c4] = *(const float4*)(Wih + (size_t)j * 272 + 256 + c4);
    }
    for (int i = tid; i < 16 * 64; i += 256) {
        int r = i >> 6, k4 = (i & 63) * 4;
        *(float4*)&linlds[r][k4] = *(const float4*)(lin_w + r * 256 + k4);
    }
    float cstate = 0.f;
    __syncthreads();

    for (int t = 0; t <= TSEQ; ++t) {
        // prefetch this step's Gd value (independent of h) before the wait
        float gval = 0.f;
        if (t < TSEQ)
            gval = Gd[((size_t)t * NB + bg * 4 + bb_t) * 1024 + jrow];

        // barrier: the 16 blocks of our batch-group published h(t-1).
        // RELAXED polls only (flag is an agent atomic -> L3-coherent).
        if (t > 0 && tid < 16) {
            while (__hip_atomic_load(&flags[bg * 16 + tid], __ATOMIC_RELAXED,
                                     __HIP_MEMORY_SCOPE_AGENT) < t)
                __builtin_amdgcn_s_sleep(1);
        }
        __syncthreads();   // orders h loads after flag observation

        // load h(t-1) for our 4 batches (relaxed agent atomics -> L3)
        const float* hsrc = hbuf + (size_t)(t & 1) * (NB * DL) + (size_t)bg * 4 * DL;
        for (int i = tid; i < 4 * DL; i += 256)
            hlds[i >> 8][i & 255] =
                __hip_atomic_load(&hsrc[i], __ATOMIC_RELAXED, __HIP_MEMORY_SCOPE_AGENT);
        __syncthreads();

        // y(t-1) = softmax(lin_w @ h(t-1) + lin_b), all 256 threads:
        // wave y_bb, lane = y_cls*4 + y_seg; each lane does a 64-length dot.
        {
            float yv;
            if (t == 0) {
                yv = 0.f;
            } else {
                float p = 0.f;
                const float* lrow = &linlds[y_cls][y_seg * 64];
                const float* hrow = &hlds[y_bb][y_seg * 64];
#pragma unroll
                for (int k4 = 0; k4 < 16; ++k4) {
                    float4 w = *(const float4*)(lrow + k4 * 4);
                    float4 h = *(const float4*)(hrow + k4 * 4);
                    p += w.x * h.x + w.y * h.y + w.z * h.z + w.w * h.w;
                }
                p += __shfl_xor(p, 1);
                p += __shfl_xor(p, 2);
                float logit = p + lb;
                float m = logit;
#pragma unroll
                for (int o = 4; o <= 32; o <<= 1) m = fmaxf(m, __shfl_xor(m, o));
                float e = __expf(logit - m);
                float ss = e;
#pragma unroll
                for (int o = 4; o <= 32; o <<= 1) ss += __shfl_xor(ss, o);
                yv = e / ss;
            }
            if (y_seg == 0) {
                ylds[y_bb][y_cls] = yv;
                if (t > 0 && rg == 0)
                    out[(((size_t)(bg * 4 + y_bb)) * TSEQ + (t - 1)) * NC + y_cls] = yv;
            }
        }
        __syncthreads();

        if (t == TSEQ) break;   // uniform across block

        // gates: Gd + Whh·h + Wy·y
        {
            float acc = gval;
            const float4* wrow = (const float4*)&Wlds[rr_t][0];
            const float4* hrow = (const float4*)&hlds[bb_t][0];
#pragma unroll 8
            for (int k4 = 0; k4 < 64; ++k4) {
                float4 w = wrow[k4], h = hrow[k4];
                acc += w.x * h.x + w.y * h.y + w.z * h.z + w.w * h.w;
            }
#pragma unroll
            for (int c = 0; c < 16; ++c)
                acc += Wylds[rr_t][c] * ylds[bb_t][c];
            glds[bb_t][rr_t] = acc;
        }
        __syncthreads();

        // c,h update + publish (relaxed atomic stores -> L3)
        if (tid < 64) {
            int bb = tid >> 4, u = tid & 15;
            float ig = sigf(glds[bb][u]);
            float fg = sigf(glds[bb][16 + u]);
            float gg = tanhfast(glds[bb][32 + u]);
            float og = sigf(glds[bb][48 + u]);
            cstate = fg * cstate + ig * gg;
            float h = og * tanhfast(cstate);
            float* hdst = hbuf + (size_t)((t + 1) & 1) * (NB * DL)
                        + (size_t)(bg * 4 + bb) * DL + rg * 16 + u;
            __hip_atomic_store(hdst, h, __ATOMIC_RELAXED, __HIP_MEMORY_SCOPE_AGENT);
        }
        __syncthreads();   // drains vmcnt(0): h stores complete at L3 before flag
        if (tid == 0)
            __hip_atomic_store(&flags[blk], t + 1, __ATOMIC_RELAXED,
                               __HIP_MEMORY_SCOPE_AGENT);
    }
}

// ---------------------------------------------------------------------------
extern "C" void kernel_launch(void* const* d_in, const int* in_sizes, int n_in,
                              void* d_out, int out_size, void* d_ws, size_t ws_size,
                              hipStream_t stream)
{
    const float* x     = (const float*)d_in[0];
    const int*   mask  = (const int*)d_in[1];
    const float* Wih_f = (const float*)d_in[2];
    const float* Whh_f = (const float*)d_in[3];
    const float* bih_f = (const float*)d_in[4];
    const float* bhh_f = (const float*)d_in[5];
    const float* Wih_r = (const float*)d_in[6];
    const float* Whh_r = (const float*)d_in[7];
    const float* bih_r = (const float*)d_in[8];
    const float* bhh_r = (const float*)d_in[9];
    const float* fc1_w = (const float*)d_in[10];
    const float* fc2_w = (const float*)d_in[11];
    const float* fc3_w = (const float*)d_in[12];
    const float* fc3_b = (const float*)d_in[13];
    const float* Wih_d = (const float*)d_in[14];
    const float* Whh_d = (const float*)d_in[15];
    const float* bih_d = (const float*)d_in[16];
    const float* bhh_d = (const float*)d_in[17];
    const float* lin_w = (const float*)d_in[18];
    const float* lin_b = (const float*)d_in[19];

    float* ws = (float*)d_ws;
    // layout (floats): Gf[8M] Gr[8M] hs[8M] wat[8M] qp[160K] kp[160K]
    float* Gf   = ws;
    float* Gr   = ws + 8388608;
    float* hs   = ws + 16777216;   // (NB*T, 512) = [h_fwd | h_rev | ctx]
    float* wat  = ws + 25165824;   // attention weights (NB,T,T); later y_enc
    float* qp   = ws + 33554432;
    float* kp   = ws + 33718272;
    float* Gd   = ws;              // reuse Gf+Gr region (16M floats)
    float* yenc = wat;             // reuse wat region: yenc = wat[0 : 4M)
    float* hbuf = wat + 4194304;   // dead upper half of wat after kernel 7
    int*   flags = (int*)(wat + 4194304 + 2 * NB * DL);

    float* outp = (float*)d_out;
    const int M = NB * TSEQ;       // 16384
    dim3 blk(256);

    // 1-2. encoder input projections (biases folded in), time-major outputs
    gemm_nt<1><<<dim3(M / 64, 8), blk, 0, stream>>>(x, DB, Wih_f, DB, bih_f, bhh_f, Gf, 512, 512, DB);
    gemm_nt<2><<<dim3(M / 64, 8), blk, 0, stream>>>(x, DB, Wih_r, DB, bih_r, bhh_r, Gr, 512, 512, DB);
    // 3. bidirectional recurrence
    enc_scan<<<dim3(64), dim3(512), 0, stream>>>(Gf, Gr, Whh_f, Whh_r, hs);
    // 4-5. q/k projections (fc1 split)
    gemm_nt<0><<<dim3(M / 64, 1), blk, 0, stream>>>(hs, 512, fc1_w, 512, nullptr, nullptr, qp, 10, 10, 256);
    gemm_nt<0><<<dim3(M / 64, 1), blk, 0, stream>>>(hs, 512, fc1_w + 256, 512, nullptr, nullptr, kp, 10, 10, 256);
    // 6. attention scores + softmax
    attn_w<<<dim3(M), blk, 0, stream>>>(qp, kp, mask, fc2_w, wat);
    // 7. ctx = w @ hs  (writes hs cols 256:512)
    bgemm_nn<<<dim3(8, 4, NB), blk, 0, stream>>>(wat, hs);
    // 8. y_enc = [hs|ctx] @ fc3^T + b   (into wat[0:4M))
    gemm_nt<0><<<dim3(M / 64, 4), blk, 0, stream>>>(hs, 512, fc3_w, 512, fc3_b, nullptr, yenc, 256, 256, 512);
    // 8.5 decoder state init (after wat's attention use is done)
    dec_init<<<dim3(1), blk, 0, stream>>>(hs, hbuf, flags);
    // 9. decoder input projection, biases folded, time-major
    gemm_nt<1><<<dim3(M / 64, 16), blk, 0, stream>>>(yenc, 256, Wih_d, 272, bih_d, bhh_d, Gd, 1024, 1024, 256);
    // 10. decoder recurrence + classifier softmax (weight-stationary, flag barrier)
    dec_scan2<<<dim3(128), blk, 0, stream>>>(Gd, Whh_d, Wih_d, lin_w, lin_b, hbuf, flags, outp);
}

// Round 5
// 3646.790 us; speedup vs baseline: 4.5479x; 1.3336x over previous
//
#include <hip/hip_runtime.h>

// Problem constants
#define TSEQ 512
#define NB   32     // batch
#define DB   768    // d_bert
#define H2E  128    // encoder hidden per dir
#define DL   256    // d_lstm
#define NC   16     // n_class

__device__ __forceinline__ float sigf(float x) { return 1.0f / (1.0f + __expf(-x)); }
__device__ __forceinline__ float tanhfast(float x) { return 1.0f - 2.0f / (1.0f + __expf(2.0f * x)); }

// ---------------------------------------------------------------------------
// Generic f32 GEMM: C[remap(m), n] = sum_k A[m,k]*W[n,k] + b1[n] + b2[n]
// 64x64 tile, BK=16, 256 threads, 4x4 microtile.
// MODE 0: direct rows. MODE 1: m=b*T+t -> out row t*NB+b. MODE 2: -> (T-1-t)*NB+b.
// ---------------------------------------------------------------------------
template <int MODE>
__global__ __launch_bounds__(256) void gemm_nt(
    const float* __restrict__ A, int lda,
    const float* __restrict__ W, int ldw,
    const float* __restrict__ b1, const float* __restrict__ b2,
    float* __restrict__ C, int ldc, int N, int K)
{
    __shared__ float As[16][68];
    __shared__ float Ws[16][68];
    const int tid = threadIdx.x;
    const int m0 = blockIdx.x * 64;
    const int n0 = blockIdx.y * 64;
    const int tx = tid & 15, ty = tid >> 4;
    const int lrow = tid >> 2;
    const int lk = (tid & 3) * 4;
    float acc[4][4] = {};

    for (int k0 = 0; k0 < K; k0 += 16) {
        float4 av = *(const float4*)(A + (size_t)(m0 + lrow) * lda + k0 + lk);
        float4 wv = make_float4(0.f, 0.f, 0.f, 0.f);
        if (n0 + lrow < N)
            wv = *(const float4*)(W + (size_t)(n0 + lrow) * ldw + k0 + lk);
        As[lk + 0][lrow] = av.x; As[lk + 1][lrow] = av.y;
        As[lk + 2][lrow] = av.z; As[lk + 3][lrow] = av.w;
        Ws[lk + 0][lrow] = wv.x; Ws[lk + 1][lrow] = wv.y;
        Ws[lk + 2][lrow] = wv.z; Ws[lk + 3][lrow] = wv.w;
        __syncthreads();
#pragma unroll
        for (int kk = 0; kk < 16; ++kk) {
            float a0 = As[kk][ty * 4 + 0], a1 = As[kk][ty * 4 + 1];
            float a2 = As[kk][ty * 4 + 2], a3 = As[kk][ty * 4 + 3];
            float w0 = Ws[kk][tx * 4 + 0], w1 = Ws[kk][tx * 4 + 1];
            float w2 = Ws[kk][tx * 4 + 2], w3 = Ws[kk][tx * 4 + 3];
            acc[0][0] += a0 * w0; acc[0][1] += a0 * w1; acc[0][2] += a0 * w2; acc[0][3] += a0 * w3;
            acc[1][0] += a1 * w0; acc[1][1] += a1 * w1; acc[1][2] += a1 * w2; acc[1][3] += a1 * w3;
            acc[2][0] += a2 * w0; acc[2][1] += a2 * w1; acc[2][2] += a2 * w2; acc[2][3] += a2 * w3;
            acc[3][0] += a3 * w0; acc[3][1] += a3 * w1; acc[3][2] += a3 * w2; acc[3][3] += a3 * w3;
        }
        __syncthreads();
    }

#pragma unroll
    for (int i = 0; i < 4; ++i) {
        int gm = m0 + ty * 4 + i;
        int orow;
        if (MODE == 0) orow = gm;
        else {
            int bb = gm >> 9;          // /TSEQ
            int tt = gm & (TSEQ - 1);
            orow = (MODE == 1 ? tt : (TSEQ - 1 - tt)) * NB + bb;
        }
#pragma unroll
        for (int j = 0; j < 4; ++j) {
            int gn = n0 + tx * 4 + j;
            if (gn < N) {
                float bias = (b1 ? b1[gn] : 0.f) + (b2 ? b2[gn] : 0.f);
                C[(size_t)orow * ldc + gn] = acc[i][j] + bias;
            }
        }
    }
}

// ---------------------------------------------------------------------------
// Encoder LSTM scan (unchanged).
// ---------------------------------------------------------------------------
__global__ __launch_bounds__(512) void enc_scan(
    const float* __restrict__ Gf, const float* __restrict__ Gr,
    const float* __restrict__ Whh_f, const float* __restrict__ Whh_r,
    float* __restrict__ hs_ctx)
{
    const int dir = blockIdx.x & 1;
    const int b = blockIdx.x >> 1;
    const float* __restrict__ G = dir ? Gr : Gf;
    const float* __restrict__ Whh = dir ? Whh_r : Whh_f;
    const int j = threadIdx.x;   // gate 0..511

    __shared__ float4 h4[H2E / 4];
    __shared__ float gates[4 * H2E];
    float* h_s = (float*)h4;

    float4 w[32];
#pragma unroll
    for (int k = 0; k < 32; ++k)
        w[k] = *(const float4*)(Whh + (size_t)j * H2E + k * 4);

    float c = 0.f;
    if (j < H2E) h_s[j] = 0.f;
    __syncthreads();

    for (int t = 0; t < TSEQ; ++t) {
        const float* grow = G + ((size_t)t * NB + b) * 512;
        float acc = grow[j];
#pragma unroll
        for (int k = 0; k < 32; ++k) {
            float4 hv = h4[k];
            acc += w[k].x * hv.x + w[k].y * hv.y + w[k].z * hv.z + w[k].w * hv.w;
        }
        gates[j] = acc;
        __syncthreads();
        if (j < H2E) {
            float ig = sigf(gates[j]);
            float fg = sigf(gates[j + H2E]);
            float gg = tanhfast(gates[j + 2 * H2E]);
            float og = sigf(gates[j + 3 * H2E]);
            c = fg * c + ig * gg;
            float h = og * tanhfast(c);
            h_s[j] = h;
            int tout = dir ? (TSEQ - 1 - t) : t;
            hs_ctx[((size_t)b * TSEQ + tout) * 512 + dir * H2E + j] = h;
        }
        __syncthreads();
    }
}

// ---------------------------------------------------------------------------
// Fused additive-attention scores + softmax (unchanged).
// ---------------------------------------------------------------------------
__global__ __launch_bounds__(256) void attn_w(
    const float* __restrict__ qp, const float* __restrict__ kp,
    const int* __restrict__ mask, const float* __restrict__ fc2,
    float* __restrict__ wout)
{
    const int bi = blockIdx.x;       // b*T + i
    const int b = bi >> 9;
    const int tid = threadIdx.x;
    __shared__ float kps[TSEQ * 11];
    __shared__ float red[8];

    const float* kpb = kp + (size_t)b * TSEQ * 10;
    for (int idx = tid; idx < TSEQ * 10; idx += 256) {
        int j = idx / 10, xx = idx - j * 10;
        kps[j * 11 + xx] = kpb[idx];
    }
    float q[10], vv[10];
#pragma unroll
    for (int xx = 0; xx < 10; ++xx) {
        q[xx] = qp[(size_t)bi * 10 + xx];
        vv[xx] = fc2[xx];
    }
    __syncthreads();

    float a[2];
#pragma unroll
    for (int jj = 0; jj < 2; ++jj) {
        int j = tid + jj * 256;
        float s = 0.f;
#pragma unroll
        for (int xx = 0; xx < 10; ++xx)
            s += vv[xx] * tanhfast(q[xx] + kps[j * 11 + xx]);
        if (mask[(size_t)b * TSEQ + j] == 0) s = -1e30f;
        a[jj] = s;
    }

    float m = fmaxf(a[0], a[1]);
#pragma unroll
    for (int o = 32; o >= 1; o >>= 1) m = fmaxf(m, __shfl_xor(m, o));
    if ((tid & 63) == 0) red[tid >> 6] = m;
    __syncthreads();
    m = fmaxf(fmaxf(red[0], red[1]), fmaxf(red[2], red[3]));

    float e0 = __expf(a[0] - m), e1 = __expf(a[1] - m);
    float s = e0 + e1;
#pragma unroll
    for (int o = 32; o >= 1; o >>= 1) s += __shfl_xor(s, o);
    if ((tid & 63) == 0) red[4 + (tid >> 6)] = s;
    __syncthreads();
    s = (red[4] + red[5]) + (red[6] + red[7]);
    float inv = 1.0f / s;
    wout[(size_t)bi * TSEQ + tid] = e0 * inv;
    wout[(size_t)bi * TSEQ + tid + 256] = e1 * inv;
}

// ---------------------------------------------------------------------------
// Batched NN GEMM: ctx = w @ hs (unchanged).
// ---------------------------------------------------------------------------
__global__ __launch_bounds__(256) void bgemm_nn(
    const float* __restrict__ Wmat,  // (NB, T, T)
    float* __restrict__ hs_ctx)      // (NB*T, 512): read cols [0,256), write [256,512)
{
    __shared__ float As[16][68];
    __shared__ float Bs[16][68];
    const int tid = threadIdx.x;
    const int b = blockIdx.z;
    const int i0 = blockIdx.x * 64;
    const int d0 = blockIdx.y * 64;
    const int tx = tid & 15, ty = tid >> 4;
    float acc[4][4] = {};
    const float* Ab = Wmat + (size_t)b * TSEQ * TSEQ;
    const float* Bb = hs_ctx + (size_t)b * TSEQ * 512;

    for (int k0 = 0; k0 < TSEQ; k0 += 16) {
        {
            int r = tid >> 2, kq = (tid & 3) * 4;
            float4 v = *(const float4*)(Ab + (size_t)(i0 + r) * TSEQ + k0 + kq);
            As[kq + 0][r] = v.x; As[kq + 1][r] = v.y; As[kq + 2][r] = v.z; As[kq + 3][r] = v.w;
        }
        {
            int kk = tid >> 4, dq = (tid & 15) * 4;
            float4 v = *(const float4*)(Bb + (size_t)(k0 + kk) * 512 + d0 + dq);
            *(float4*)&Bs[kk][dq] = v;
        }
        __syncthreads();
#pragma unroll
        for (int kk = 0; kk < 16; ++kk) {
            float a0 = As[kk][ty * 4 + 0], a1 = As[kk][ty * 4 + 1];
            float a2 = As[kk][ty * 4 + 2], a3 = As[kk][ty * 4 + 3];
            float b0 = Bs[kk][tx * 4 + 0], b1 = Bs[kk][tx * 4 + 1];
            float b2 = Bs[kk][tx * 4 + 2], b3 = Bs[kk][tx * 4 + 3];
            acc[0][0] += a0 * b0; acc[0][1] += a0 * b1; acc[0][2] += a0 * b2; acc[0][3] += a0 * b3;
            acc[1][0] += a1 * b0; acc[1][1] += a1 * b1; acc[1][2] += a1 * b2; acc[1][3] += a1 * b3;
            acc[2][0] += a2 * b0; acc[2][1] += a2 * b1; acc[2][2] += a2 * b2; acc[2][3] += a2 * b3;
            acc[3][0] += a3 * b0; acc[3][1] += a3 * b1; acc[3][2] += a3 * b2; acc[3][3] += a3 * b3;
        }
        __syncthreads();
    }
#pragma unroll
    for (int i = 0; i < 4; ++i)
#pragma unroll
        for (int j = 0; j < 4; ++j)
            hs_ctx[((size_t)b * TSEQ + i0 + ty * 4 + i) * 512 + 256 + d0 + tx * 4 + j] = acc[i][j];
}

// ---------------------------------------------------------------------------
// Decoder init: h(-1) = hs[:, T-1, :DL] into hbuf[0]; zero the 128 flags.
// ---------------------------------------------------------------------------
__global__ __launch_bounds__(256) void dec_init(
    const float* __restrict__ hs_ctx, float* hbuf, int* flags)
{
    const int tid = threadIdx.x;
    if (tid < 128)
        __hip_atomic_store(&flags[tid], 0, __ATOMIC_RELAXED, __HIP_MEMORY_SCOPE_AGENT);
    for (int i = tid; i < NB * DL; i += 256) {
        int bb = i >> 8, u = i & 255;
        float v = hs_ctx[((size_t)bb * TSEQ + (TSEQ - 1)) * 512 + u];
        __hip_atomic_store(&hbuf[i], v, __ATOMIC_RELAXED, __HIP_MEMORY_SCOPE_AGENT);
    }
}

// ---------------------------------------------------------------------------
// Decoder scan v4 (layout-fixed): weights in REGISTERS, LDS broadcast-only
// reads, partial-logit publish. 128 blocks = 16 row-groups x 8 batch-groups.
// Thread = (kseg = tid>>6 [wave], rr = tid&63). Thread holds Whh[jrow]
// k-segment [kseg*64, kseg*64+64) in 16 float4 regs. Gate dot reads h via
// wave-uniform (broadcast) LDS addresses. Per-(batch,class) logit partials
// for THIS block's 16 h-units are published alongside h; readers sum 16
// partials + shuffle-softmax (replaces the per-block 16x256 y-dot).
// Cross-block traffic: RELAXED agent atomics only (L3-coherent, no L2 inv).
// ---------------------------------------------------------------------------
__global__ __launch_bounds__(256) void dec_scan3(
    const float* __restrict__ Gd,     // (T, NB, 1024), biases folded
    const float* __restrict__ Whh,    // (1024, 256)
    const float* __restrict__ Wih,    // (1024, 272); cols 256:272 multiply y
    const float* __restrict__ lin_w,  // (16, 256)
    const float* __restrict__ lin_b,  // (16,)
    float* hbuf,                      // (2, NB, DL)
    float* lbuf,                      // (2, NB, 16rg, 16cls) logit partials
    int* flags,                       // (128,)
    float* __restrict__ out)          // (NB, T, NC)
{
    const int tid = threadIdx.x;
    const int rg  = blockIdx.x & 15;
    const int bg  = blockIdx.x >> 4;
    const int blk = blockIdx.x;
    const int kseg = tid >> 6;        // wave id 0..3 (wave-uniform)
    const int rr   = tid & 63;        // gate row 0..63 within block
    const int jrow = ((rr >> 4) << 8) + rg * 16 + (rr & 15);

    __shared__ float hlds[4][260];    // h(t-1) for 4 batches
    __shared__ float part[4][4][66];  // [bb][kseg][rr] gate partials (pad: <=2-way)
    __shared__ float ylds[4][16];     // y(t-1)
    __shared__ float hnew[4][16];     // this block's new h slice
    __shared__ float linl[16][17];    // lin_w[cls][rg*16+u]

    // ---- weights into registers (one-time) ----
    float4 w[16];
    {
        const float* wrow = Whh + (size_t)jrow * 256 + kseg * 64;
#pragma unroll
        for (int i = 0; i < 16; ++i) w[i] = *(const float4*)(wrow + i * 4);
    }
    const float4 wy = *(const float4*)(Wih + (size_t)jrow * 272 + 256 + kseg * 4);
    linl[tid >> 4][tid & 15] = lin_w[(tid >> 4) * 256 + rg * 16 + (tid & 15)];
    const float lb = lin_b[tid & 15];

    float cstate = 0.f;               // live in tid<64: (bb=tid>>4, u=tid&15)
    __syncthreads();

    for (int t = 0; t <= TSEQ; ++t) {
        // prefetch Gd (independent of h) before the wait; wave 0 only
        float gv0 = 0.f, gv1 = 0.f, gv2 = 0.f, gv3 = 0.f;
        if (kseg == 0 && t < TSEQ) {
            const float* gbase = Gd + ((size_t)t * NB + bg * 4) * 1024 + jrow;
            gv0 = gbase[0]; gv1 = gbase[1024]; gv2 = gbase[2048]; gv3 = gbase[3072];
        }

        // barrier: the 16 blocks of our batch-group published step t-1
        if (t > 0 && tid < 16) {
            while (__hip_atomic_load(&flags[bg * 16 + tid], __ATOMIC_RELAXED,
                                     __HIP_MEMORY_SCOPE_AGENT) < t)
                __builtin_amdgcn_s_sleep(1);
        }
        __syncthreads();

        // load h(t-1) for our 4 batches (atomic relaxed -> L3-coherent)
        const float* hsrc = hbuf + (size_t)(t & 1) * (NB * DL) + (size_t)bg * 4 * DL;
        for (int i = tid; i < 4 * DL; i += 256)
            hlds[i >> 8][i & 255] =
                __hip_atomic_load(&hsrc[i], __ATOMIC_RELAXED, __HIP_MEMORY_SCOPE_AGENT);

        // y(t-1): sum 16 logit partials per (bb,cls) + 16-lane shuffle softmax
        if (tid < 64) {
            const int bb = tid >> 4, cls = tid & 15;
            float yv;
            if (t == 0) {
                yv = 0.f;
            } else {
                const float* lrow = lbuf + (size_t)(t & 1) * (NB * 256)
                                  + (size_t)(bg * 4 + bb) * 256 + cls;
                float lp = lb;
#pragma unroll
                for (int r = 0; r < 16; ++r)
                    lp += __hip_atomic_load(lrow + r * 16, __ATOMIC_RELAXED,
                                            __HIP_MEMORY_SCOPE_AGENT);
                float m = lp;
#pragma unroll
                for (int o = 1; o < 16; o <<= 1) m = fmaxf(m, __shfl_xor(m, o, 16));
                float e = __expf(lp - m);
                float ss = e;
#pragma unroll
                for (int o = 1; o < 16; o <<= 1) ss += __shfl_xor(ss, o, 16);
                yv = e / ss;
                if (rg == 0)
                    out[(((size_t)(bg * 4 + bb)) * TSEQ + (t - 1)) * NC + cls] = yv;
            }
            ylds[bb][cls] = yv;
        }
        __syncthreads();   // hlds + ylds ready

        if (t == TSEQ) break;   // uniform across block

        // gate partials: all LDS reads are wave-uniform broadcasts
        {
            float a0, a1, a2, a3;
            a0 = wy.x * ylds[0][kseg * 4 + 0] + wy.y * ylds[0][kseg * 4 + 1]
               + wy.z * ylds[0][kseg * 4 + 2] + wy.w * ylds[0][kseg * 4 + 3];
            a1 = wy.x * ylds[1][kseg * 4 + 0] + wy.y * ylds[1][kseg * 4 + 1]
               + wy.z * ylds[1][kseg * 4 + 2] + wy.w * ylds[1][kseg * 4 + 3];
            a2 = wy.x * ylds[2][kseg * 4 + 0] + wy.y * ylds[2][kseg * 4 + 1]
               + wy.z * ylds[2][kseg * 4 + 2] + wy.w * ylds[2][kseg * 4 + 3];
            a3 = wy.x * ylds[3][kseg * 4 + 0] + wy.y * ylds[3][kseg * 4 + 1]
               + wy.z * ylds[3][kseg * 4 + 2] + wy.w * ylds[3][kseg * 4 + 3];
            if (kseg == 0) { a0 += gv0; a1 += gv1; a2 += gv2; a3 += gv3; }
#pragma unroll
            for (int i = 0; i < 16; ++i) {
                const float4 wv = w[i];
                const int kc = kseg * 64 + i * 4;
                float4 h0 = *(const float4*)&hlds[0][kc];
                float4 h1 = *(const float4*)&hlds[1][kc];
                float4 h2 = *(const float4*)&hlds[2][kc];
                float4 h3 = *(const float4*)&hlds[3][kc];
                a0 += wv.x * h0.x + wv.y * h0.y + wv.z * h0.z + wv.w * h0.w;
                a1 += wv.x * h1.x + wv.y * h1.y + wv.z * h1.z + wv.w * h1.w;
                a2 += wv.x * h2.x + wv.y * h2.y + wv.z * h2.z + wv.w * h2.w;
                a3 += wv.x * h3.x + wv.y * h3.y + wv.z * h3.z + wv.w * h3.w;
            }
            part[0][kseg][rr] = a0;
            part[1][kseg][rr] = a1;
            part[2][kseg][rr] = a2;
            part[3][kseg][rr] = a3;
        }
        __syncthreads();

        // finalize: reduce 4 ksegs, nonlinearity, h update, partial logits
        if (tid < 64) {
            const int bb = tid >> 4, u = tid & 15;
            float gi = 0.f, gf = 0.f, gg = 0.f, go = 0.f;
#pragma unroll
            for (int ks = 0; ks < 4; ++ks) {
                gi += part[bb][ks][u];
                gf += part[bb][ks][u + 16];
                gg += part[bb][ks][u + 32];
                go += part[bb][ks][u + 48];
            }
            float ig = sigf(gi), fg = sigf(gf);
            float gv = tanhfast(gg), og = sigf(go);
            cstate = fg * cstate + ig * gv;
            float h = og * tanhfast(cstate);
            hnew[bb][u] = h;
            float* hdst = hbuf + (size_t)((t + 1) & 1) * (NB * DL)
                        + (size_t)(bg * 4 + bb) * DL + rg * 16 + u;
            __hip_atomic_store(hdst, h, __ATOMIC_RELAXED, __HIP_MEMORY_SCOPE_AGENT);
            // partial logits for (bb, cls=u): dot over our 16 h-units.
            // hnew write->read is wave-0-internal (lockstep, lgkmcnt ordered).
            const int cls = u;
            float lp = 0.f;
#pragma unroll
            for (int u2 = 0; u2 < 16; ++u2)
                lp += linl[cls][u2] * hnew[bb][u2];
            float* ldst = lbuf + (size_t)((t + 1) & 1) * (NB * 256)
                        + (size_t)(bg * 4 + bb) * 256 + rg * 16 + cls;
            __hip_atomic_store(ldst, lp, __ATOMIC_RELAXED, __HIP_MEMORY_SCOPE_AGENT);
        }
        __syncthreads();   // drains vmcnt(0): publishes complete before flag
        if (tid == 0)
            __hip_atomic_store(&flags[blk], t + 1, __ATOMIC_RELAXED,
                               __HIP_MEMORY_SCOPE_AGENT);
    }
}

// ---------------------------------------------------------------------------
extern "C" void kernel_launch(void* const* d_in, const int* in_sizes, int n_in,
                              void* d_out, int out_size, void* d_ws, size_t ws_size,
                              hipStream_t stream)
{
    const float* x     = (const float*)d_in[0];
    const int*   mask  = (const int*)d_in[1];
    const float* Wih_f = (const float*)d_in[2];
    const float* Whh_f = (const float*)d_in[3];
    const float* bih_f = (const float*)d_in[4];
    const float* bhh_f = (const float*)d_in[5];
    const float* Wih_r = (const float*)d_in[6];
    const float* Whh_r = (const float*)d_in[7];
    const float* bih_r = (const float*)d_in[8];
    const float* bhh_r = (const float*)d_in[9];
    const float* fc1_w = (const float*)d_in[10];
    const float* fc2_w = (const float*)d_in[11];
    const float* fc3_w = (const float*)d_in[12];
    const float* fc3_b = (const float*)d_in[13];
    const float* Wih_d = (const float*)d_in[14];
    const float* Whh_d = (const float*)d_in[15];
    const float* bih_d = (const float*)d_in[16];
    const float* bhh_d = (const float*)d_in[17];
    const float* lin_w = (const float*)d_in[18];
    const float* lin_b = (const float*)d_in[19];

    float* ws = (float*)d_ws;
    // layout (floats): Gf[8M] Gr[8M] hs[8M] wat[8M] qp[160K] kp[160K]
    float* Gf   = ws;
    float* Gr   = ws + 8388608;
    float* hs   = ws + 16777216;   // (NB*T, 512) = [h_fwd | h_rev | ctx]
    float* wat  = ws + 25165824;   // attention weights (NB,T,T); later reused
    float* qp   = ws + 33554432;
    float* kp   = ws + 33718272;
    float* Gd   = ws;              // reuse Gf+Gr region (16M floats)
    float* yenc = wat;             // reuse wat region: yenc = wat[0 : 4M)
    // decoder comm region (dead upper half of wat after kernel 7):
    //   hbuf: 2*NB*DL = 16384 floats
    //   flags: 128 ints, padded to 256 float slots   <-- FIX: was 64, aliased lbuf
    //   lbuf: 2*NB*256 = 16384 floats
    float* hbuf  = wat + 4194304;
    int*   flags = (int*)(wat + 4194304 + 2 * NB * DL);
    float* lbuf  = wat + 4194304 + 2 * NB * DL + 256;

    float* outp = (float*)d_out;
    const int M = NB * TSEQ;       // 16384
    dim3 blk(256);

    // 1-2. encoder input projections (biases folded in), time-major outputs
    gemm_nt<1><<<dim3(M / 64, 8), blk, 0, stream>>>(x, DB, Wih_f, DB, bih_f, bhh_f, Gf, 512, 512, DB);
    gemm_nt<2><<<dim3(M / 64, 8), blk, 0, stream>>>(x, DB, Wih_r, DB, bih_r, bhh_r, Gr, 512, 512, DB);
    // 3. bidirectional recurrence
    enc_scan<<<dim3(64), dim3(512), 0, stream>>>(Gf, Gr, Whh_f, Whh_r, hs);
    // 4-5. q/k projections (fc1 split)
    gemm_nt<0><<<dim3(M / 64, 1), blk, 0, stream>>>(hs, 512, fc1_w, 512, nullptr, nullptr, qp, 10, 10, 256);
    gemm_nt<0><<<dim3(M / 64, 1), blk, 0, stream>>>(hs, 512, fc1_w + 256, 512, nullptr, nullptr, kp, 10, 10, 256);
    // 6. attention scores + softmax
    attn_w<<<dim3(M), blk, 0, stream>>>(qp, kp, mask, fc2_w, wat);
    // 7. ctx = w @ hs  (writes hs cols 256:512)
    bgemm_nn<<<dim3(8, 4, NB), blk, 0, stream>>>(wat, hs);
    // 8. y_enc = [hs|ctx] @ fc3^T + b   (into wat[0:4M))
    gemm_nt<0><<<dim3(M / 64, 4), blk, 0, stream>>>(hs, 512, fc3_w, 512, fc3_b, nullptr, yenc, 256, 256, 512);
    // 8.5 decoder state init (after wat's attention use is done)
    dec_init<<<dim3(1), blk, 0, stream>>>(hs, hbuf, flags);
    // 9. decoder input projection, biases folded, time-major
    gemm_nt<1><<<dim3(M / 64, 16), blk, 0, stream>>>(yenc, 256, Wih_d, 272, bih_d, bhh_d, Gd, 1024, 1024, 256);
    // 10. decoder recurrence + classifier softmax (register-stationary weights)
    dec_scan3<<<dim3(128), blk, 0, stream>>>(Gd, Whh_d, Wih_d, lin_w, lin_b, hbuf, lbuf, flags, outp);
}